// Round 2
// baseline (432.577 us; speedup 1.0000x reference)
//
#include <hip/hip_runtime.h>
#include <hip/hip_bf16.h>
#include <cstdint>
#include <cstddef>

// ---------------- problem constants ----------------
#define T_TOK   4096      // B*L tokens
#define LSEQ    2048
#define DMODEL  1024
#define DINNER  2048
#define DTRANK  64
#define NSTATE  16
#define NCH     32        // scan chunks per sequence
#define LCH     64        // steps per chunk (NCH*LCH = LSEQ)
#define EPS_RMS 1.1920928955078125e-07f

typedef short b16x8 __attribute__((ext_vector_type(8)));   // 8 bf16 payload (4 VGPRs)
typedef float f32x4 __attribute__((ext_vector_type(4)));

__device__ __forceinline__ float bf2f(const __hip_bfloat16 v){ return __bfloat162float(v); }
__device__ __forceinline__ __hip_bfloat16 f2bf(const float f){ return __float2bfloat16(f); }

__device__ __forceinline__ void glds16(const void* g, void* l){
  __builtin_amdgcn_global_load_lds(
      (const __attribute__((address_space(1))) unsigned int*)g,
      (__attribute__((address_space(3))) unsigned int*)l,
      16, 0, 0);
}

__device__ __forceinline__ float softplusf(float x){
  return (x > 20.f) ? x : log1pf(__expf(x));
}
__device__ __forceinline__ float siluf(float x){
  return x / (1.f + __expf(-x));
}

// ---------------- f32 -> bf16 weight conversion ----------------
__global__ __launch_bounds__(256) void f2b_k(const float* __restrict__ in,
                                             __hip_bfloat16* __restrict__ out, int n){
  int i = blockIdx.x*256 + threadIdx.x;
  if (i < n) out[i] = f2bf(in[i]);
}

// pad rows [validRows, totRows) with zeros (row-major, width cols)
__global__ __launch_bounds__(256) void f2b_pad_k(const float* __restrict__ in,
                                                 __hip_bfloat16* __restrict__ out,
                                                 int validRows, int cols, int totRows){
  int i = blockIdx.x*256 + threadIdx.x;
  if (i < totRows*cols){
    int r = i / cols;
    out[i] = (r < validRows) ? f2bf(in[i]) : f2bf(0.f);
  }
}

// ---------------- RMSNorm: x (T,1024) f32 -> h (T,1024) bf16 ----------------
__global__ __launch_bounds__(256) void rmsnorm_k(const float* __restrict__ x,
                                                 const float* __restrict__ w,
                                                 __hip_bfloat16* __restrict__ h){
  const int t   = blockIdx.x;
  const int tid = threadIdx.x;
  const float4 v = ((const float4*)(x + (size_t)t*DMODEL))[tid];
  float ss = v.x*v.x + v.y*v.y + v.z*v.z + v.w*v.w;
  #pragma unroll
  for (int o = 1; o < 64; o <<= 1) ss += __shfl_xor(ss, o);
  __shared__ float red[4];
  const int wid = tid >> 6, lane = tid & 63;
  if (lane == 0) red[wid] = ss;
  __syncthreads();
  ss = red[0] + red[1] + red[2] + red[3];
  const float sc = rsqrtf(ss * (1.f/DMODEL) + EPS_RMS);
  const float4 wv = ((const float4*)w)[tid];
  __hip_bfloat16* hp = h + (size_t)t*DMODEL + tid*4;
  hp[0] = f2bf(v.x*sc*wv.x); hp[1] = f2bf(v.y*sc*wv.y);
  hp[2] = f2bf(v.z*sc*wv.z); hp[3] = f2bf(v.w*sc*wv.w);
}

// ---------------- bf16 GEMM:  C(M,N) = A(M,K) @ B(N,K)^T  ----------------
// 128x128 tile, BK=32, 4 waves (2x2 of 64x64), 16x16x32 MFMA, global_load_lds(16B).
// OUT_BF16: write bf16, else f32.  RESID: add f32 residual (same layout as C).
template<bool OUT_BF16, bool RESID>
__global__ __launch_bounds__(256) void gemm_bt(const __hip_bfloat16* __restrict__ A, int lda,
                                               const __hip_bfloat16* __restrict__ B, int ldb,
                                               void* __restrict__ C, int ldc,
                                               const float* __restrict__ resid,
                                               int M, int N, int K){
  __shared__ __align__(16) __hip_bfloat16 As[128*32];
  __shared__ __align__(16) __hip_bfloat16 Bs[128*32];
  const int tid  = threadIdx.x;
  const int lane = tid & 63;
  const int wid  = tid >> 6;
  const size_t row0 = (size_t)blockIdx.y * 128;
  const size_t col0 = (size_t)blockIdx.x * 128;
  const int wr = (wid >> 1) * 64;     // wave row offset in tile
  const int wc = (wid & 1) * 64;      // wave col offset in tile

  f32x4 acc[4][4];
  #pragma unroll
  for (int i = 0; i < 4; i++)
    #pragma unroll
    for (int j = 0; j < 4; j++) acc[i][j] = (f32x4){0.f, 0.f, 0.f, 0.f};

  const __hip_bfloat16* Ag = A + row0 * lda;
  const __hip_bfloat16* Bg = B + col0 * ldb;

  for (int kk = 0; kk < K; kk += 32){
    // stage A,B tiles: 512 x 16B segments each; seg -> (row=seg>>2, col8=(seg&3)*8)
    #pragma unroll
    for (int j = 0; j < 2; j++){
      const int seg = j*256 + tid;
      const int r = seg >> 2, c = (seg & 3) * 8;
      glds16(Ag + (size_t)r*lda + kk + c, (char*)As + (size_t)seg*16);
      glds16(Bg + (size_t)r*ldb + kk + c, (char*)Bs + (size_t)seg*16);
    }
    asm volatile("s_waitcnt vmcnt(0)" ::: "memory");
    __syncthreads();

    b16x8 af[4], bfr[4];
    #pragma unroll
    for (int mt = 0; mt < 4; mt++)
      af[mt] = *(const b16x8*)(As + (size_t)(wr + mt*16 + (lane & 15))*32 + 8*(lane >> 4));
    #pragma unroll
    for (int nt = 0; nt < 4; nt++)
      bfr[nt] = *(const b16x8*)(Bs + (size_t)(wc + nt*16 + (lane & 15))*32 + 8*(lane >> 4));
    #pragma unroll
    for (int mt = 0; mt < 4; mt++)
      #pragma unroll
      for (int nt = 0; nt < 4; nt++)
        acc[mt][nt] = __builtin_amdgcn_mfma_f32_16x16x32_bf16(af[mt], bfr[nt], acc[mt][nt], 0, 0, 0);
    __syncthreads();
  }

  // epilogue: C/D layout col=lane&15, row=(lane>>4)*4+j   [m89-verified]
  const int crow = (lane >> 4) * 4, ccol = lane & 15;
  #pragma unroll
  for (int mt = 0; mt < 4; mt++){
    #pragma unroll
    for (int nt = 0; nt < 4; nt++){
      const size_t gr = row0 + wr + mt*16 + crow;
      const size_t gc = col0 + wc + nt*16 + ccol;
      #pragma unroll
      for (int j = 0; j < 4; j++){
        float v = acc[mt][nt][j];
        const size_t off = (gr + j) * (size_t)ldc + gc;
        if (RESID) v += resid[off];
        if (OUT_BF16) ((__hip_bfloat16*)C)[off] = f2bf(v);
        else          ((float*)C)[off] = v;
      }
    }
  }
}

// ---------------- causal depthwise conv (K=4) + SiLU ----------------
// u = xz[:, 0:2048];  uc[t,d] = silu(conv_b[d] + sum_k u[t-3+k, d] * conv_w[d,k])
__global__ __launch_bounds__(256) void conv_silu_k(const __hip_bfloat16* __restrict__ xz,
                                                   const float* __restrict__ cw,
                                                   const float* __restrict__ cb,
                                                   __hip_bfloat16* __restrict__ uc){
  const int idx = blockIdx.x*256 + threadIdx.x;   // t*2048 + d
  const int d = idx & (DINNER-1);
  const int t = idx >> 11;
  const int l = t & (LSEQ-1);
  float acc = cb[d];
  #pragma unroll
  for (int k = 0; k < 4; k++){
    const int lp = l + k - 3;
    if (lp >= 0)
      acc += bf2f(xz[(size_t)(t + k - 3)*(2*DINNER) + d]) * cw[d*4 + k];
  }
  uc[idx] = f2bf(siluf(acc));
}

// ---------------- selective scan (3-phase chunked linear scan) ----------------
// phase 1: per (b, chunk, d): local scan with h0=0; emit end-state h and prod(dA)
__global__ __launch_bounds__(256) void scan1_k(const __hip_bfloat16* __restrict__ dtp,
                                               const __hip_bfloat16* __restrict__ uc,
                                               const __hip_bfloat16* __restrict__ xdbl,
                                               const float* __restrict__ A_log,
                                               const float* __restrict__ dtb,
                                               float* __restrict__ hloc,
                                               float* __restrict__ pA){
  const int gid = blockIdx.x*256 + threadIdx.x;   // (b*NCH + c)*2048 + d
  const int d  = gid & (DINNER-1);
  const int bc = gid >> 11;
  const int c  = bc & (NCH-1);
  const int b  = bc >> 5;
  float a[NSTATE], h[NSTATE], p[NSTATE];
  #pragma unroll
  for (int n = 0; n < NSTATE; n++){
    a[n] = -__expf(A_log[d*NSTATE + n]);
    h[n] = 0.f; p[n] = 1.f;
  }
  const float bias = dtb[d];
  const int t0 = b*LSEQ + c*LCH;
  for (int l = 0; l < LCH; l++){
    const size_t t = t0 + l;
    const float dt  = softplusf(bf2f(dtp[t*DINNER + d]) + bias);
    const float u   = bf2f(uc[t*DINNER + d]);
    const float dtu = dt * u;
    const __hip_bfloat16* Bv = xdbl + t*128 + DTRANK;
    #pragma unroll
    for (int n = 0; n < NSTATE; n++){
      const float e = __expf(dt * a[n]);
      h[n] = e*h[n] + dtu * bf2f(Bv[n]);
      p[n] *= e;
    }
  }
  float* hp = hloc + (size_t)gid*NSTATE;
  float* pp = pA   + (size_t)gid*NSTATE;
  #pragma unroll
  for (int n = 0; n < NSTATE; n++){ hp[n] = h[n]; pp[n] = p[n]; }
}

// phase 2: per (b,d,n): sequential combine over chunks -> initial state per chunk
__global__ __launch_bounds__(256) void scan2_k(const float* __restrict__ hloc,
                                               const float* __restrict__ pA,
                                               float* __restrict__ init){
  const int gid = blockIdx.x*256 + threadIdx.x;   // (b*2048 + d)*16 + n
  const int n = gid & (NSTATE-1);
  const int d = (gid >> 4) & (DINNER-1);
  const int b = gid >> 15;
  float S = 0.f;
  for (int c = 0; c < NCH; c++){
    const size_t off = (((size_t)(b*NCH + c)*DINNER + d) << 4) + n;
    init[off] = S;
    S = pA[off]*S + hloc[off];
  }
}

// phase 3: re-scan with correct initial state; y = <h,C>; fuse +uc*D, *silu(z); bf16 out
__global__ __launch_bounds__(256) void scan3_k(const __hip_bfloat16* __restrict__ dtp,
                                               const __hip_bfloat16* __restrict__ uc,
                                               const __hip_bfloat16* __restrict__ xdbl,
                                               const __hip_bfloat16* __restrict__ xz,
                                               const float* __restrict__ A_log,
                                               const float* __restrict__ dtb,
                                               const float* __restrict__ Dw,
                                               const float* __restrict__ init,
                                               __hip_bfloat16* __restrict__ yg){
  const int gid = blockIdx.x*256 + threadIdx.x;   // (b*NCH + c)*2048 + d
  const int d  = gid & (DINNER-1);
  const int bc = gid >> 11;
  const int c  = bc & (NCH-1);
  const int b  = bc >> 5;
  float a[NSTATE], h[NSTATE];
  const float* ip = init + (size_t)gid*NSTATE;
  #pragma unroll
  for (int n = 0; n < NSTATE; n++){
    a[n] = -__expf(A_log[d*NSTATE + n]);
    h[n] = ip[n];
  }
  const float bias = dtb[d];
  const float Dd = Dw[d];
  const int t0 = b*LSEQ + c*LCH;
  for (int l = 0; l < LCH; l++){
    const size_t t = t0 + l;
    const float dt  = softplusf(bf2f(dtp[t*DINNER + d]) + bias);
    const float u   = bf2f(uc[t*DINNER + d]);
    const float dtu = dt * u;
    const __hip_bfloat16* Bv = xdbl + t*128 + DTRANK;
    const __hip_bfloat16* Cv = xdbl + t*128 + DTRANK + NSTATE;
    float y = 0.f;
    #pragma unroll
    for (int n = 0; n < NSTATE; n++){
      const float e = __expf(dt * a[n]);
      h[n] = e*h[n] + dtu * bf2f(Bv[n]);
      y += h[n] * bf2f(Cv[n]);
    }
    const float z = bf2f(xz[t*(2*DINNER) + DINNER + d]);
    yg[t*DINNER + d] = f2bf((y + u*Dd) * siluf(z));
  }
}

// ---------------- host launcher ----------------
extern "C" void kernel_launch(void* const* d_in, const int* in_sizes, int n_in,
                              void* d_out, int out_size, void* d_ws, size_t ws_size,
                              hipStream_t stream){
  const float* x       = (const float*)d_in[0];
  const float* norm_w  = (const float*)d_in[1];
  const float* in_pw   = (const float*)d_in[2];
  const float* conv_w  = (const float*)d_in[3];
  const float* conv_b  = (const float*)d_in[4];
  const float* x_pw    = (const float*)d_in[5];
  const float* dt_pw   = (const float*)d_in[6];
  const float* dt_pb   = (const float*)d_in[7];
  const float* A_log   = (const float*)d_in[8];
  const float* Dw      = (const float*)d_in[9];
  const float* out_pw  = (const float*)d_in[10];
  float* out = (float*)d_out;

  // workspace carve (aligned 256B).
  // NOTE: yg16 aliases [h16, win16] — both dead after GEMM1; yg first written in scan3.
  char* p = (char*)d_ws;
  auto carve = [&](size_t bytes) -> char* {
    char* r = p;
    p += (bytes + 255) & ~(size_t)255;
    return r;
  };
  __hip_bfloat16* h16    = (__hip_bfloat16*)carve((size_t)T_TOK*DMODEL*2);      // 8 MB
  __hip_bfloat16* win16  = (__hip_bfloat16*)carve((size_t)2*DINNER*DMODEL*2);   // 8 MB
  __hip_bfloat16* xz16   = (__hip_bfloat16*)carve((size_t)T_TOK*2*DINNER*2);    // 32 MB
  __hip_bfloat16* uc16   = (__hip_bfloat16*)carve((size_t)T_TOK*DINNER*2);      // 16 MB
  __hip_bfloat16* wxp16  = (__hip_bfloat16*)carve((size_t)128*DINNER*2);        // 0.5 MB
  __hip_bfloat16* xdbl16 = (__hip_bfloat16*)carve((size_t)T_TOK*128*2);         // 1 MB
  __hip_bfloat16* wdt16  = (__hip_bfloat16*)carve((size_t)DINNER*DTRANK*2);     // 0.25 MB
  __hip_bfloat16* dtp16  = (__hip_bfloat16*)carve((size_t)T_TOK*DINNER*2);      // 16 MB
  __hip_bfloat16* wout16 = (__hip_bfloat16*)carve((size_t)DMODEL*DINNER*2);     // 4 MB
  float* hloc = (float*)carve((size_t)2*NCH*DINNER*NSTATE*4);                   // 8 MB
  float* pA   = (float*)carve((size_t)2*NCH*DINNER*NSTATE*4);                   // 8 MB
  float* init = (float*)carve((size_t)2*NCH*DINNER*NSTATE*4);                   // 8 MB
  __hip_bfloat16* yg16   = (__hip_bfloat16*)h16;                                // alias, 16 MB

  // weight conversions
  {
    int n = 2*DINNER*DMODEL;
    f2b_k<<<(n+255)/256, 256, 0, stream>>>(in_pw, win16, n);
    n = 128*DINNER;
    f2b_pad_k<<<(n+255)/256, 256, 0, stream>>>(x_pw, wxp16, DTRANK + 2*NSTATE, DINNER, 128);
    n = DINNER*DTRANK;
    f2b_k<<<(n+255)/256, 256, 0, stream>>>(dt_pw, wdt16, n);
    n = DMODEL*DINNER;
    f2b_k<<<(n+255)/256, 256, 0, stream>>>(out_pw, wout16, n);
  }

  // RMSNorm
  rmsnorm_k<<<T_TOK, 256, 0, stream>>>(x, norm_w, h16);

  // GEMM1: xz = h @ in_proj^T   (4096 x 4096 x 1024)
  gemm_bt<true, false><<<dim3(2*DINNER/128, T_TOK/128), 256, 0, stream>>>(
      h16, DMODEL, win16, DMODEL, xz16, 2*DINNER, nullptr, T_TOK, 2*DINNER, DMODEL);

  // conv + SiLU
  conv_silu_k<<<(T_TOK*DINNER)/256, 256, 0, stream>>>(xz16, conv_w, conv_b, uc16);

  // GEMM2: x_dbl = uc @ x_proj^T   (4096 x 128(pad96) x 2048)
  gemm_bt<true, false><<<dim3(1, T_TOK/128), 256, 0, stream>>>(
      uc16, DINNER, wxp16, DINNER, xdbl16, 128, nullptr, T_TOK, 128, DINNER);

  // GEMM3: dt_pre = x_dbl[:, :64] @ dt_proj^T   (4096 x 2048 x 64)
  gemm_bt<true, false><<<dim3(DINNER/128, T_TOK/128), 256, 0, stream>>>(
      xdbl16, 128, wdt16, DTRANK, dtp16, DINNER, nullptr, T_TOK, DINNER, DTRANK);

  // selective scan
  scan1_k<<<(2*NCH*DINNER)/256, 256, 0, stream>>>(dtp16, uc16, xdbl16, A_log, dt_pb, hloc, pA);
  scan2_k<<<(2*DINNER*NSTATE)/256, 256, 0, stream>>>(hloc, pA, init);
  scan3_k<<<(2*NCH*DINNER)/256, 256, 0, stream>>>(dtp16, uc16, xdbl16, xz16,
                                                  A_log, dt_pb, Dw, init, yg16);

  // GEMM4: out = yg @ out_proj^T + x   (4096 x 1024 x 2048)
  gemm_bt<false, true><<<dim3(DMODEL/128, T_TOK/128), 256, 0, stream>>>(
      yg16, DINNER, wout16, DINNER, out, DMODEL, x, T_TOK, DMODEL, DINNER);
}

// Round 4
// 365.042 us; speedup vs baseline: 1.1850x; 1.1850x over previous
//
#include <hip/hip_runtime.h>
#include <hip/hip_bf16.h>
#include <cstdint>
#include <cstddef>

// ---------------- problem constants ----------------
#define T_TOK   4096      // B*L tokens
#define LSEQ    2048
#define DMODEL  1024
#define DINNER  2048
#define DTRANK  64
#define NSTATE  16
#define NCH     64        // scan chunks per sequence
#define NCH_LOG 6
#define LCH     32        // steps per chunk (NCH*LCH = LSEQ)
#define EPS_RMS 1.1920928955078125e-07f

typedef short b16x8 __attribute__((ext_vector_type(8)));   // 8 bf16 payload (4 VGPRs)
typedef short s16x4 __attribute__((ext_vector_type(4)));
typedef float f32x4 __attribute__((ext_vector_type(4)));

__device__ __forceinline__ float bf2f(const __hip_bfloat16 v){ return __bfloat162float(v); }
__device__ __forceinline__ __hip_bfloat16 f2bf(const float f){ return __float2bfloat16(f); }
__device__ __forceinline__ float bfbits(short s){
  union { unsigned u; float f; } v; v.u = ((unsigned)(unsigned short)s) << 16; return v.f;
}
__device__ __forceinline__ short f2bs(float f){
  __hip_bfloat16 h = __float2bfloat16(f);
  return *reinterpret_cast<short*>(&h);
}

__device__ __forceinline__ void glds16(const void* g, void* l){
  __builtin_amdgcn_global_load_lds(
      (const __attribute__((address_space(1))) unsigned int*)g,
      (__attribute__((address_space(3))) unsigned int*)l,
      16, 0, 0);
}

__device__ __forceinline__ float softplusf(float x){
  return (x > 20.f) ? x : log1pf(__expf(x));
}
__device__ __forceinline__ float siluf(float x){
  return x / (1.f + __expf(-x));
}

// ---------------- f32 -> bf16 weight conversion (x4 vectorized) ----------------
__global__ __launch_bounds__(256) void f2b4_k(const float4* __restrict__ in,
                                              s16x4* __restrict__ out, int n4){
  int i = blockIdx.x*256 + threadIdx.x;
  if (i < n4){
    float4 v = in[i];
    s16x4 o;
    o[0] = f2bs(v.x); o[1] = f2bs(v.y); o[2] = f2bs(v.z); o[3] = f2bs(v.w);
    out[i] = o;
  }
}

// pad rows [validRows, totRows) with zeros (row-major, width cols)
__global__ __launch_bounds__(256) void f2b_pad_k(const float* __restrict__ in,
                                                 __hip_bfloat16* __restrict__ out,
                                                 int validRows, int cols, int totRows){
  int i = blockIdx.x*256 + threadIdx.x;
  if (i < totRows*cols){
    int r = i / cols;
    out[i] = (r < validRows) ? f2bf(in[i]) : f2bf(0.f);
  }
}

// ---------------- RMSNorm: x (T,1024) f32 -> h (T,1024) bf16 ----------------
__global__ __launch_bounds__(256) void rmsnorm_k(const float* __restrict__ x,
                                                 const float* __restrict__ w,
                                                 __hip_bfloat16* __restrict__ h){
  const int t   = blockIdx.x;
  const int tid = threadIdx.x;
  const float4 v = ((const float4*)(x + (size_t)t*DMODEL))[tid];
  float ss = v.x*v.x + v.y*v.y + v.z*v.z + v.w*v.w;
  #pragma unroll
  for (int o = 1; o < 64; o <<= 1) ss += __shfl_xor(ss, o);
  __shared__ float red[4];
  const int wid = tid >> 6, lane = tid & 63;
  if (lane == 0) red[wid] = ss;
  __syncthreads();
  ss = red[0] + red[1] + red[2] + red[3];
  const float sc = rsqrtf(ss * (1.f/DMODEL) + EPS_RMS);
  const float4 wv = ((const float4*)w)[tid];
  __hip_bfloat16* hp = h + (size_t)t*DMODEL + tid*4;
  hp[0] = f2bf(v.x*sc*wv.x); hp[1] = f2bf(v.y*sc*wv.y);
  hp[2] = f2bf(v.z*sc*wv.z); hp[3] = f2bf(v.w*sc*wv.w);
}

// ---------------- bf16 GEMM:  C(M,N) = A(M,K) @ B(N,K)^T  ----------------
// 128x128 tile, BK=32, 4 waves (2x2 of 64x64), 16x16x32 MFMA, global_load_lds(16B).
// OUT_BF16: write bf16, else f32.  RESID: add f32 residual.  SPLIT: cols >= DINNER
// go to C2 (col-2048), both ldc.  Split-K via blockIdx.z: A,B advance z*K in K-dim,
// C advances z*M*ldc (f32 partial mode).
template<bool OUT_BF16, bool RESID, bool SPLIT>
__global__ __launch_bounds__(256) void gemm_bt(const __hip_bfloat16* __restrict__ A, int lda,
                                               const __hip_bfloat16* __restrict__ B, int ldb,
                                               void* __restrict__ C, int ldc,
                                               const float* __restrict__ resid,
                                               int M, int N, int K,
                                               void* __restrict__ C2){
  // XCD-aware swizzle (all grids used are multiples of 8 workgroups in x*y)
  const int nbx = gridDim.x;
  const int nwg = nbx * gridDim.y;
  const int lin = blockIdx.y * nbx + blockIdx.x;
  const int swz = (lin & 7) * (nwg >> 3) + (lin >> 3);
  const int bx = swz % nbx, by = swz / nbx;

  __shared__ __align__(16) __hip_bfloat16 As[128*32];
  __shared__ __align__(16) __hip_bfloat16 Bs[128*32];
  const int tid  = threadIdx.x;
  const int lane = tid & 63;
  const int wid  = tid >> 6;
  const size_t row0 = (size_t)by * 128;
  size_t col0       = (size_t)bx * 128;
  const int wr = (wid >> 1) * 64;     // wave row offset in tile
  const int wc = (wid & 1) * 64;      // wave col offset in tile

  f32x4 acc[4][4];
  #pragma unroll
  for (int i = 0; i < 4; i++)
    #pragma unroll
    for (int j = 0; j < 4; j++) acc[i][j] = (f32x4){0.f, 0.f, 0.f, 0.f};

  const size_t koff = (size_t)blockIdx.z * K;
  const __hip_bfloat16* Ag = A + row0 * lda + koff;
  const __hip_bfloat16* Bg = B + col0 * ldb + koff;
  char* Cb = (char*)C + (size_t)blockIdx.z * (size_t)M * ldc * (OUT_BF16 ? 2 : 4);
  if (SPLIT && col0 >= DINNER){ Cb = (char*)C2; col0 -= DINNER; }

  for (int kk = 0; kk < K; kk += 32){
    // stage A,B tiles: 512 x 16B segments each; seg -> (row=seg>>2, col8=(seg&3)*8)
    #pragma unroll
    for (int j = 0; j < 2; j++){
      const int seg = j*256 + tid;
      const int r = seg >> 2, c = (seg & 3) * 8;
      glds16(Ag + (size_t)r*lda + kk + c, (char*)As + (size_t)seg*16);
      glds16(Bg + (size_t)r*ldb + kk + c, (char*)Bs + (size_t)seg*16);
    }
    asm volatile("s_waitcnt vmcnt(0)" ::: "memory");
    __syncthreads();

    b16x8 af[4], bfr[4];
    #pragma unroll
    for (int mt = 0; mt < 4; mt++)
      af[mt] = *(const b16x8*)(As + (size_t)(wr + mt*16 + (lane & 15))*32 + 8*(lane >> 4));
    #pragma unroll
    for (int nt = 0; nt < 4; nt++)
      bfr[nt] = *(const b16x8*)(Bs + (size_t)(wc + nt*16 + (lane & 15))*32 + 8*(lane >> 4));
    #pragma unroll
    for (int mt = 0; mt < 4; mt++)
      #pragma unroll
      for (int nt = 0; nt < 4; nt++)
        acc[mt][nt] = __builtin_amdgcn_mfma_f32_16x16x32_bf16(af[mt], bfr[nt], acc[mt][nt], 0, 0, 0);
    __syncthreads();
  }

  // epilogue: C/D layout col=lane&15, row=(lane>>4)*4+j   [m89-verified]
  const int crow = (lane >> 4) * 4, ccol = lane & 15;
  #pragma unroll
  for (int mt = 0; mt < 4; mt++){
    #pragma unroll
    for (int nt = 0; nt < 4; nt++){
      const size_t gr = row0 + wr + mt*16 + crow;
      const size_t gc = col0 + wc + nt*16 + ccol;
      #pragma unroll
      for (int j = 0; j < 4; j++){
        float v = acc[mt][nt][j];
        const size_t off = (gr + j) * (size_t)ldc + gc;
        if (RESID) v += resid[off];
        if (OUT_BF16) ((__hip_bfloat16*)Cb)[off] = f2bf(v);
        else          ((float*)Cb)[off] = v;
      }
    }
  }
}

// ---------------- split-K reduce: xdbl = bf16(sum_z partial[z]) ----------------
__global__ __launch_bounds__(256) void redu8_k(const float* __restrict__ part,
                                               __hip_bfloat16* __restrict__ out){
  const int n = T_TOK*128;
  int i = blockIdx.x*256 + threadIdx.x;
  float s = 0.f;
  #pragma unroll
  for (int z = 0; z < 8; z++) s += part[(size_t)z*n + i];
  out[i] = f2bf(s);
}

// ---------------- causal depthwise conv (K=4) + SiLU, 8 d per thread ----------------
__global__ __launch_bounds__(256) void conv_silu_k(const __hip_bfloat16* __restrict__ u,
                                                   const float* __restrict__ cw,
                                                   const float* __restrict__ cb,
                                                   __hip_bfloat16* __restrict__ uc){
  const int g  = blockIdx.x*256 + threadIdx.x;  // one t per block, 256 d-groups of 8
  const int d0 = (g & 255) * 8;
  const int t  = g >> 8;
  const int l  = t & (LSEQ-1);
  float acc[8];
  #pragma unroll
  for (int j = 0; j < 8; j++) acc[j] = cb[d0+j];
  #pragma unroll
  for (int k = 0; k < 4; k++){
    const int lp = l + k - 3;
    if (lp >= 0){
      const b16x8 v = *(const b16x8*)(u + (size_t)(t + k - 3)*DINNER + d0);
      #pragma unroll
      for (int j = 0; j < 8; j++) acc[j] += bfbits(v[j]) * cw[(d0+j)*4 + k];
    }
  }
  b16x8 o;
  #pragma unroll
  for (int j = 0; j < 8; j++) o[j] = f2bs(siluf(acc[j]));
  *(b16x8*)(uc + (size_t)t*DINNER + d0) = o;
}

// ---------------- selective scan (3-phase chunked linear scan) ----------------
// phase 1: per (b, chunk, d): local scan with h0=0; emit end-state h and prod(dA)
__global__ __launch_bounds__(256) void scan1_k(const __hip_bfloat16* __restrict__ dtp,
                                               const __hip_bfloat16* __restrict__ uc,
                                               const __hip_bfloat16* __restrict__ xdbl,
                                               const float* __restrict__ A_log,
                                               const float* __restrict__ dtb,
                                               float* __restrict__ hloc,
                                               float* __restrict__ pA){
  const int gid = blockIdx.x*256 + threadIdx.x;   // (b*NCH + c)*2048 + d
  const int d  = gid & (DINNER-1);
  const int bc = gid >> 11;
  const int c  = bc & (NCH-1);
  const int b  = bc >> NCH_LOG;
  float a[NSTATE], h[NSTATE], p[NSTATE];
  #pragma unroll
  for (int n = 0; n < NSTATE; n++){
    a[n] = -__expf(A_log[d*NSTATE + n]);
    h[n] = 0.f; p[n] = 1.f;
  }
  const float bias = dtb[d];
  const int t0 = b*LSEQ + c*LCH;
  #pragma unroll 2
  for (int l = 0; l < LCH; l++){
    const size_t t = t0 + l;
    const float dt  = softplusf(bf2f(dtp[t*DINNER + d]) + bias);
    const float u   = bf2f(uc[t*DINNER + d]);
    const float dtu = dt * u;
    const b16x8 bv0 = *(const b16x8*)(xdbl + t*128 + DTRANK);
    const b16x8 bv1 = *(const b16x8*)(xdbl + t*128 + DTRANK + 8);
    #pragma unroll
    for (int n = 0; n < 8; n++){
      const float e = __expf(dt * a[n]);
      h[n] = e*h[n] + dtu * bfbits(bv0[n]);
      p[n] *= e;
    }
    #pragma unroll
    for (int n = 0; n < 8; n++){
      const float e = __expf(dt * a[8+n]);
      h[8+n] = e*h[8+n] + dtu * bfbits(bv1[n]);
      p[8+n] *= e;
    }
  }
  float* hp = hloc + (size_t)gid*NSTATE;
  float* pp = pA   + (size_t)gid*NSTATE;
  #pragma unroll
  for (int n = 0; n < NSTATE; n++){ hp[n] = h[n]; pp[n] = p[n]; }
}

// phase 2: per (b,d,n): sequential combine over chunks -> initial state per chunk
__global__ __launch_bounds__(256) void scan2_k(const float* __restrict__ hloc,
                                               const float* __restrict__ pA,
                                               float* __restrict__ init){
  const int gid = blockIdx.x*256 + threadIdx.x;   // (b*2048 + d)*16 + n
  const int n = gid & (NSTATE-1);
  const int d = (gid >> 4) & (DINNER-1);
  const int b = gid >> 15;
  float S = 0.f;
  #pragma unroll 4
  for (int c = 0; c < NCH; c++){
    const size_t off = (((size_t)(b*NCH + c)*DINNER + d) << 4) + n;
    init[off] = S;
    S = pA[off]*S + hloc[off];
  }
}

// phase 3: re-scan with correct initial state; y = <h,C>; fuse +uc*D, *silu(z); bf16 out
__global__ __launch_bounds__(256) void scan3_k(const __hip_bfloat16* __restrict__ dtp,
                                               const __hip_bfloat16* __restrict__ uc,
                                               const __hip_bfloat16* __restrict__ xdbl,
                                               const __hip_bfloat16* __restrict__ z16,
                                               const float* __restrict__ A_log,
                                               const float* __restrict__ dtb,
                                               const float* __restrict__ Dw,
                                               const float* __restrict__ init,
                                               __hip_bfloat16* __restrict__ yg){
  const int gid = blockIdx.x*256 + threadIdx.x;   // (b*NCH + c)*2048 + d
  const int d  = gid & (DINNER-1);
  const int bc = gid >> 11;
  const int c  = bc & (NCH-1);
  const int b  = bc >> NCH_LOG;
  float a[NSTATE], h[NSTATE];
  const float* ip = init + (size_t)gid*NSTATE;
  #pragma unroll
  for (int n = 0; n < NSTATE; n++){
    a[n] = -__expf(A_log[d*NSTATE + n]);
    h[n] = ip[n];
  }
  const float bias = dtb[d];
  const float Dd = Dw[d];
  const int t0 = b*LSEQ + c*LCH;
  #pragma unroll 2
  for (int l = 0; l < LCH; l++){
    const size_t t = t0 + l;
    const float dt  = softplusf(bf2f(dtp[t*DINNER + d]) + bias);
    const float u   = bf2f(uc[t*DINNER + d]);
    const float dtu = dt * u;
    const b16x8 bv0 = *(const b16x8*)(xdbl + t*128 + DTRANK);
    const b16x8 bv1 = *(const b16x8*)(xdbl + t*128 + DTRANK + 8);
    const b16x8 cv0 = *(const b16x8*)(xdbl + t*128 + DTRANK + NSTATE);
    const b16x8 cv1 = *(const b16x8*)(xdbl + t*128 + DTRANK + NSTATE + 8);
    float y = 0.f;
    #pragma unroll
    for (int n = 0; n < 8; n++){
      const float e = __expf(dt * a[n]);
      h[n] = e*h[n] + dtu * bfbits(bv0[n]);
      y += h[n] * bfbits(cv0[n]);
    }
    #pragma unroll
    for (int n = 0; n < 8; n++){
      const float e = __expf(dt * a[8+n]);
      h[8+n] = e*h[8+n] + dtu * bfbits(bv1[n]);
      y += h[8+n] * bfbits(cv1[n]);
    }
    const float z = bf2f(z16[t*DINNER + d]);
    yg[t*DINNER + d] = f2bf((y + u*Dd) * siluf(z));
  }
}

// ---------------- host launcher ----------------
extern "C" void kernel_launch(void* const* d_in, const int* in_sizes, int n_in,
                              void* d_out, int out_size, void* d_ws, size_t ws_size,
                              hipStream_t stream){
  const float* x       = (const float*)d_in[0];
  const float* norm_w  = (const float*)d_in[1];
  const float* in_pw   = (const float*)d_in[2];
  const float* conv_w  = (const float*)d_in[3];
  const float* conv_b  = (const float*)d_in[4];
  const float* x_pw    = (const float*)d_in[5];
  const float* dt_pw   = (const float*)d_in[6];
  const float* dt_pb   = (const float*)d_in[7];
  const float* A_log   = (const float*)d_in[8];
  const float* Dw      = (const float*)d_in[9];
  const float* out_pw  = (const float*)d_in[10];
  float* out = (float*)d_out;

  // ---- workspace carve with lifetime-based aliasing (peak ~102 MB) ----
  // S0: u16[GEMM1..conv] -> hloc[scan1..scan2] -> yg16[scan3..GEMM4]
  // S1: h16(8MB)+win16(8MB)[..GEMM1] -> pA[scan1..scan2]
  // S4: partial[GEMM2] -> init[scan2..scan3]
  char* p = (char*)d_ws;
  auto carve = [&](size_t bytes) -> char* {
    char* r = p;
    p += (bytes + 255) & ~(size_t)255;
    return r;
  };
  const size_t MB16 = (size_t)16*1024*1024;
  char* S0 = carve(MB16);
  char* S1 = carve(MB16);
  char* S2 = carve(MB16);
  char* S3 = carve(MB16);
  char* S4 = carve(MB16);
  char* S5 = carve(MB16);
  char* S6 = carve((size_t)DMODEL*DINNER*2);   // wout16, 4 MB
  char* S7 = carve((size_t)128*DINNER*2);      // wxp16, 0.5 MB
  char* S8 = carve((size_t)DINNER*DTRANK*2);   // wdt16, 0.25 MB
  char* S9 = carve((size_t)T_TOK*128*2);       // xdbl16, 1 MB

  __hip_bfloat16* u16    = (__hip_bfloat16*)S0;
  float*          hloc   = (float*)S0;
  __hip_bfloat16* yg16   = (__hip_bfloat16*)S0;
  __hip_bfloat16* h16    = (__hip_bfloat16*)S1;
  __hip_bfloat16* win16  = (__hip_bfloat16*)(S1 + (size_t)T_TOK*DMODEL*2);
  float*          pA     = (float*)S1;
  __hip_bfloat16* z16    = (__hip_bfloat16*)S2;
  __hip_bfloat16* uc16   = (__hip_bfloat16*)S3;
  float*          partial= (float*)S4;
  float*          init   = (float*)S4;
  __hip_bfloat16* dtp16  = (__hip_bfloat16*)S5;
  __hip_bfloat16* wout16 = (__hip_bfloat16*)S6;
  __hip_bfloat16* wxp16  = (__hip_bfloat16*)S7;
  __hip_bfloat16* wdt16  = (__hip_bfloat16*)S8;
  __hip_bfloat16* xdbl16 = (__hip_bfloat16*)S9;

  // weight conversions (vectorized x4)
  f2b4_k<<<(2*DINNER*DMODEL/4 + 255)/256, 256, 0, stream>>>(
      (const float4*)in_pw, (s16x4*)win16, 2*DINNER*DMODEL/4);
  f2b_pad_k<<<(128*DINNER + 255)/256, 256, 0, stream>>>(
      x_pw, wxp16, DTRANK + 2*NSTATE, DINNER, 128);
  f2b4_k<<<(DINNER*DTRANK/4 + 255)/256, 256, 0, stream>>>(
      (const float4*)dt_pw, (s16x4*)wdt16, DINNER*DTRANK/4);
  f2b4_k<<<(DMODEL*DINNER/4 + 255)/256, 256, 0, stream>>>(
      (const float4*)out_pw, (s16x4*)wout16, DMODEL*DINNER/4);

  // RMSNorm
  rmsnorm_k<<<T_TOK, 256, 0, stream>>>(x, norm_w, h16);

  // GEMM1: [u|z] = h @ in_proj^T   (4096 x 4096 x 1024), split outputs
  gemm_bt<true, false, true><<<dim3(2*DINNER/128, T_TOK/128), 256, 0, stream>>>(
      h16, DMODEL, win16, DMODEL, u16, DINNER, nullptr, T_TOK, 2*DINNER, DMODEL, z16);

  // conv + SiLU
  conv_silu_k<<<T_TOK, 256, 0, stream>>>(u16, conv_w, conv_b, uc16);

  // GEMM2: x_dbl = uc @ x_proj^T   (4096 x 128(pad96) x 2048), split-K x8
  gemm_bt<false, false, false><<<dim3(1, T_TOK/128, 8), 256, 0, stream>>>(
      uc16, DINNER, wxp16, DINNER, partial, 128, nullptr, T_TOK, 128, DINNER/8, nullptr);
  redu8_k<<<(T_TOK*128)/256, 256, 0, stream>>>(partial, xdbl16);

  // GEMM3: dt_pre = x_dbl[:, :64] @ dt_proj^T   (4096 x 2048 x 64)
  gemm_bt<true, false, false><<<dim3(DINNER/128, T_TOK/128), 256, 0, stream>>>(
      xdbl16, 128, wdt16, DTRANK, dtp16, DINNER, nullptr, T_TOK, DINNER, DTRANK, nullptr);

  // selective scan
  scan1_k<<<(2*NCH*DINNER)/256, 256, 0, stream>>>(dtp16, uc16, xdbl16, A_log, dt_pb, hloc, pA);
  scan2_k<<<(2*DINNER*NSTATE)/256, 256, 0, stream>>>(hloc, pA, init);
  scan3_k<<<(2*NCH*DINNER)/256, 256, 0, stream>>>(dtp16, uc16, xdbl16, z16,
                                                  A_log, dt_pb, Dw, init, yg16);

  // GEMM4: out = yg @ out_proj^T + x   (4096 x 1024 x 2048)
  gemm_bt<false, true, false><<<dim3(DMODEL/128, T_TOK/128), 256, 0, stream>>>(
      yg16, DINNER, wout16, DINNER, out, DMODEL, x, T_TOK, DMODEL, DINNER, nullptr);
}